// Round 7
// baseline (520.823 us; speedup 1.0000x reference)
//
#include <hip/hip_runtime.h>
#include <hip/hip_cooperative_groups.h>

namespace cg = cooperative_groups;

#define SEQ 2048
#define DIM 1024

typedef __attribute__((ext_vector_type(8))) __bf16 bf16x8;
typedef __attribute__((ext_vector_type(4))) float f32x4;

typedef __attribute__((address_space(1))) unsigned char gu8_t;
typedef __attribute__((address_space(3))) unsigned char lu8_t;

__device__ __forceinline__ void async_copy16(const void* g, void* l) {
  __builtin_amdgcn_global_load_lds((gu8_t*)g, (lu8_t*)l, 16, 0, 0);
}

__device__ __forceinline__ ushort f2bf(float f) {
  union { float f; unsigned u; } v;
  v.f = f;
  unsigned r = v.u + 0x7FFFu + ((v.u >> 16) & 1u);
  return (ushort)(r >> 16);
}

// ============================================================================
// gemm_core: the R2-proven 256x256 BK=64 8-wave 8-phase engine with counted
// vmcnt (conflicts=0, VGPR 116, no spill). Function-scope __shared__ keeps
// all LDS accesses in ds_* form (one static allocation shared by all inlined
// call sites within `fused`). Epilogue: runtime isE (exp+causal+lsum) vs
// scale+store (both bf16 out).
// ============================================================================
__device__ __forceinline__ void gemm_core(
    const ushort* __restrict__ A, const ushort* __restrict__ B,
    ushort* __restrict__ C, float* __restrict__ ls, const bool isE,
    const int m0, const int n0, const long ldA, const long ldB,
    const long ldC, const float scale) {
  __shared__ ushort sA[2][2][8192];
  __shared__ ushort sB[2][2][8192];

  constexpr int nT = 16;  // K = 1024 for all users

  const int tid = threadIdx.x;
  const int lane = tid & 63;
  const int w = tid >> 6;        // 0..7
  const int quad = lane >> 4;    // 0..3
  const int l15 = lane & 15;
  const int ah = w >> 2;         // A half owned by this wave
  const int wn = (w & 3) << 6;   // 0,64,128,192 within N-256
  const int bh = wn >> 7;        // B half
  const int bo = wn & 64;        // row offset within B half

  // Pre-swizzled global stage sources: LDS linear pos g holds global chunk
  // (g&7)^(row&7) of row g>>3.
  const ushort* aSrc[2][2];
  const ushort* bSrc[2][2];
#pragma unroll
  for (int h = 0; h < 2; h++)
#pragma unroll
    for (int i = 0; i < 2; i++) {
      const int g = i * 512 + tid;
      const int rl = g >> 3;
      const int ck = (g & 7) ^ (rl & 7);
      aSrc[h][i] = A + (size_t)(m0 + h * 128 + rl) * ldA + ck * 8;
      bSrc[h][i] = B + (size_t)(n0 + h * 128 + rl) * ldB + ck * 8;
    }

  auto stageA = [&](int t, int b) {
#pragma unroll
    for (int h = 0; h < 2; h++)
#pragma unroll
      for (int i = 0; i < 2; i++)
        async_copy16(aSrc[h][i] + t * 64, &sA[b][h][(i * 512 + tid) * 8]);
  };
  auto stageB = [&](int t, int b) {
#pragma unroll
    for (int h = 0; h < 2; h++)
#pragma unroll
      for (int i = 0; i < 2; i++)
        async_copy16(bSrc[h][i] + t * 64, &sB[b][h][(i * 512 + tid) * 8]);
  };
  auto rdA = [&](int b, int rbase, int kh) -> bf16x8 {
    const int row = rbase + l15;
    const int ck = ((kh << 2) | quad) ^ (row & 7);
    return *(const bf16x8*)&sA[b][ah][row * 64 + ck * 8];
  };
  auto rdB = [&](int b, int rbase, int kh) -> bf16x8 {
    const int row = rbase + l15;
    const int ck = ((kh << 2) | quad) ^ (row & 7);
    return *(const bf16x8*)&sB[b][bh][row * 64 + ck * 8];
  };

  f32x4 acc[8][4] = {};
  bf16x8 aF[8], bF0[4], bF1[4];

  // Prologue: tiles 0 and 1 in flight; wait for tile 0 (8 newest stay out).
  stageA(0, 0); stageB(0, 0);
  stageA(1, 1); stageB(1, 1);
  asm volatile("s_waitcnt vmcnt(8)" ::: "memory");
  __builtin_amdgcn_s_barrier();

#pragma unroll 1
  for (int t = 0; t < nT; t++) {
    const int b = t & 1;

    // --- phase 1 ---
#pragma unroll
    for (int m = 0; m < 4; m++)
#pragma unroll
      for (int h = 0; h < 2; h++) aF[m * 2 + h] = rdA(b, m * 16, h);
#pragma unroll
    for (int n = 0; n < 2; n++)
#pragma unroll
      for (int h = 0; h < 2; h++) bF0[n * 2 + h] = rdB(b, bo + n * 16, h);
    __builtin_amdgcn_s_barrier();
    __builtin_amdgcn_s_setprio(1);
#pragma unroll
    for (int h = 0; h < 2; h++)
#pragma unroll
      for (int m = 0; m < 4; m++)
#pragma unroll
        for (int n = 0; n < 2; n++)
          acc[m][n] = __builtin_amdgcn_mfma_f32_16x16x32_bf16(
              aF[m * 2 + h], bF0[n * 2 + h], acc[m][n], 0, 0, 0);
    __builtin_amdgcn_s_setprio(0);
    __builtin_amdgcn_s_barrier();

    // --- phase 2 ---
#pragma unroll
    for (int n = 0; n < 2; n++)
#pragma unroll
      for (int h = 0; h < 2; h++)
        bF1[n * 2 + h] = rdB(b, bo + 32 + n * 16, h);
    __builtin_amdgcn_s_barrier();
    __builtin_amdgcn_s_setprio(1);
#pragma unroll
    for (int h = 0; h < 2; h++)
#pragma unroll
      for (int m = 0; m < 4; m++)
#pragma unroll
        for (int n = 0; n < 2; n++)
          acc[m][2 + n] = __builtin_amdgcn_mfma_f32_16x16x32_bf16(
              aF[m * 2 + h], bF1[n * 2 + h], acc[m][2 + n], 0, 0, 0);
    __builtin_amdgcn_s_setprio(0);
    __builtin_amdgcn_s_barrier();

    // --- phase 3 --- (B regions of buf b fully consumed -> safe to overwrite)
#pragma unroll
    for (int m = 0; m < 4; m++)
#pragma unroll
      for (int h = 0; h < 2; h++) aF[m * 2 + h] = rdA(b, 64 + m * 16, h);
    if (t + 2 < nT) stageB(t + 2, b);
    __builtin_amdgcn_s_barrier();
    __builtin_amdgcn_s_setprio(1);
#pragma unroll
    for (int h = 0; h < 2; h++)
#pragma unroll
      for (int m = 0; m < 4; m++)
#pragma unroll
        for (int n = 0; n < 2; n++)
          acc[4 + m][n] = __builtin_amdgcn_mfma_f32_16x16x32_bf16(
              aF[m * 2 + h], bF0[n * 2 + h], acc[4 + m][n], 0, 0, 0);
    __builtin_amdgcn_s_setprio(0);
    __builtin_amdgcn_s_barrier();

    // --- phase 4 --- (A regions fully consumed -> safe to overwrite)
    if (t + 2 < nT) stageA(t + 2, b);
    __builtin_amdgcn_s_setprio(1);
#pragma unroll
    for (int h = 0; h < 2; h++)
#pragma unroll
      for (int m = 0; m < 4; m++)
#pragma unroll
        for (int n = 0; n < 2; n++)
          acc[4 + m][2 + n] = __builtin_amdgcn_mfma_f32_16x16x32_bf16(
              aF[m * 2 + h], bF1[n * 2 + h], acc[4 + m][2 + n], 0, 0, 0);
    __builtin_amdgcn_s_setprio(0);
    if (t + 2 < nT)
      asm volatile("s_waitcnt vmcnt(8)" ::: "memory");  // tile t+1 landed
    else
      asm volatile("s_waitcnt vmcnt(0)" ::: "memory");  // drain tail
    __builtin_amdgcn_s_barrier();
  }

  if (isE) {
#pragma unroll
    for (int mi = 0; mi < 8; mi++)
#pragma unroll
      for (int r = 0; r < 4; r++) {
        const int row = m0 + ah * 128 + mi * 16 + quad * 4 + r;
        float partial = 0.0f;
#pragma unroll
        for (int ni = 0; ni < 4; ni++) {
          const int col = n0 + wn + ni * 16 + l15;
          const float ev = (col <= row) ? __expf(acc[mi][ni][r]) : 0.0f;
          C[(size_t)row * ldC + col] = f2bf(ev);
          partial += ev;
        }
#pragma unroll
        for (int o = 1; o < 16; o <<= 1) partial += __shfl_xor(partial, o, 64);
        if (l15 == 0) atomicAdd(&ls[row], partial);
      }
  } else {
#pragma unroll
    for (int mi = 0; mi < 8; mi++)
#pragma unroll
      for (int ni = 0; ni < 4; ni++)
#pragma unroll
        for (int r = 0; r < 4; r++) {
          const int row = m0 + ah * 128 + mi * 16 + quad * 4 + r;
          const int col = n0 + wn + ni * 16 + l15;
          C[(size_t)row * ldC + col] = f2bf(acc[mi][ni][r] * scale);
        }
  }
}

// ============================================================================
// fused: cooperative kernel, 256 blocks x 512 threads (1 block/CU by LDS).
//   stage P: prep (x->bf16, weight transposes 3 tiles/block, lsum zero, flag)
//   grid.sync
//   stage 1: proj Q,K -- 256 tiles = exactly 1 round
//   grid.sync
//   stage 2: VtE -- 272 tiles via u += 256 (blocks 0-15 take a 2nd tile)
// ============================================================================
__global__ __launch_bounds__(512, 2) void fused(
    const void* __restrict__ xin, const void* __restrict__ w0,
    const void* __restrict__ w1, const void* __restrict__ w2,
    ushort* __restrict__ xb, ushort* __restrict__ wt, int* __restrict__ flag,
    float* __restrict__ lsum, ushort* __restrict__ q, ushort* __restrict__ sc,
    ushort* __restrict__ vt) {
  __shared__ ushort tile[64][68];
  __shared__ int redi[8];
  const int bid = blockIdx.x;
  const int tid = threadIdx.x;
  cg::grid_group grid = cg::this_grid();

  // ---- stage P: prep ----
  // dtype detect: 512-word sample (2 KB). fp32 byte1 hit ~6% (~32/512);
  // bf16-packed ~95% (~486/512). Threshold 256.
  {
    const unsigned wv = ((const unsigned*)xin)[tid];
    const unsigned b1 = (wv >> 8) & 0x7Fu;
    int hits = (b1 >= 0x3Bu && b1 <= 0x42u) ? 1 : 0;
#pragma unroll
    for (int o = 32; o > 0; o >>= 1) hits += __shfl_xor(hits, o, 64);
    if ((tid & 63) == 0) redi[tid >> 6] = hits;
  }
  __syncthreads();
  int hsum = 0;
#pragma unroll
  for (int i = 0; i < 8; i++) hsum += redi[i];
  const int bf = (hsum > 256) ? 1 : 0;

  if (bid == 0 && tid == 0) *flag = bf;
  if (bid < 4)
    reinterpret_cast<float4*>(lsum)[bid * 512 + tid] =
        make_float4(0.f, 0.f, 0.f, 0.f);

  // x -> bf16 xb: 1M uint4 items over 256x512 threads, 8 per thread.
  if (bf) {
#pragma unroll
    for (int j = 0; j < 8; j++) {
      const int i = bid * 4096 + j * 512 + tid;
      reinterpret_cast<uint4*>(xb)[i] = reinterpret_cast<const uint4*>(xin)[i];
    }
  } else {
#pragma unroll
    for (int j = 0; j < 8; j++) {
      const int i = bid * 4096 + j * 512 + tid;
      const float4* f = reinterpret_cast<const float4*>(xin);
      const float4 a = f[2 * i], bb = f[2 * i + 1];
      ushort4 lo, hi;
      lo.x = f2bf(a.x); lo.y = f2bf(a.y); lo.z = f2bf(a.z); lo.w = f2bf(a.w);
      hi.x = f2bf(bb.x); hi.y = f2bf(bb.y); hi.z = f2bf(bb.z);
      hi.w = f2bf(bb.w);
      reinterpret_cast<ushort4*>(xb)[2 * i] = lo;
      reinterpret_cast<ushort4*>(xb)[2 * i + 1] = hi;
    }
  }

  // weight transpose: 768 64x64 tiles, 3 per block, 512 threads (2+2 iters).
#pragma unroll 1
  for (int tt = 0; tt < 3; tt++) {
    const int rem = bid * 3 + tt;
    const int z = rem >> 8;
    const int within = rem & 255;
    const int c0 = (within & 15) * 64, r0 = (within >> 4) * 64;
    const void* in = (z == 0) ? w0 : (z == 1) ? w1 : w2;
    ushort* op = wt + (size_t)z * 1048576;

    __syncthreads();
    if (bf) {
      const ushort* ip = (const ushort*)in;
#pragma unroll
      for (int i = 0; i < 2; i++) {
        const int lin = i * 512 + tid;
        const int r = lin >> 4, c4 = (lin & 15) << 2;
        const ushort4 v = *reinterpret_cast<const ushort4*>(
            ip + (size_t)(r0 + r) * 1024 + c0 + c4);
        tile[r][c4 + 0] = v.x; tile[r][c4 + 1] = v.y;
        tile[r][c4 + 2] = v.z; tile[r][c4 + 3] = v.w;
      }
    } else {
      const float* ip = (const float*)in;
#pragma unroll
      for (int i = 0; i < 2; i++) {
        const int lin = i * 512 + tid;
        const int r = lin >> 4, c4 = (lin & 15) << 2;
        const float4 v = *reinterpret_cast<const float4*>(
            ip + (size_t)(r0 + r) * 1024 + c0 + c4);
        tile[r][c4 + 0] = f2bf(v.x); tile[r][c4 + 1] = f2bf(v.y);
        tile[r][c4 + 2] = f2bf(v.z); tile[r][c4 + 3] = f2bf(v.w);
      }
    }
    __syncthreads();
#pragma unroll
    for (int i = 0; i < 2; i++) {
      const int lin = i * 512 + tid;
      const int c = lin >> 4, r4 = (lin & 15) << 2;
      ushort4 v;
      v.x = tile[r4 + 0][c]; v.y = tile[r4 + 1][c];
      v.z = tile[r4 + 2][c]; v.w = tile[r4 + 3][c];
      *reinterpret_cast<ushort4*>(op + (size_t)(c0 + c) * 1024 + r0 + r4) = v;
    }
  }

  __threadfence();
  grid.sync();
  __threadfence();

  // ---- stage 1: proj Q,K (256 tiles, 1 round) ----
  {
    const int z = bid >> 7, r = bid & 127;
    gemm_core(xb, wt + (size_t)z * 1048576, q + (size_t)z * 8388608, nullptr,
              false, (r >> 2) << 8, (r & 3) << 8, 1024, 1024, 1024,
              z ? 1.0f : 0.03125f);
  }

  __threadfence();
  grid.sync();
  __threadfence();

  // ---- stage 2: VtE (272 tiles; exact causal tri list for E) ----
#pragma unroll 1
  for (int u = bid; u < 272; u += 256) {
    if (u < 144) {
      const int z = u / 36;
      const int tri = u % 36;
      int mt = 0;
      while ((mt + 1) * (mt + 2) / 2 <= tri) mt++;
      const int nt = tri - mt * (mt + 1) / 2;
      gemm_core(q + (size_t)z * SEQ * DIM,
                q + 8388608 + (size_t)z * SEQ * DIM,
                sc + (size_t)z * SEQ * SEQ, lsum + (size_t)z * SEQ, true,
                mt << 8, nt << 8, 1024, 1024, 2048, 1.0f);
    } else {
      const int r = u - 144;
      gemm_core(wt + 2097152, xb, vt, nullptr, false, (r >> 5) << 8,
                (r & 31) << 8, 1024, 1024, 8192, 1.0f);
    }
  }
}

// Old 128x128 engine, kept for PV only (causal K-truncation load balance;
// 4 blocks/CU gives inter-block latency overlap the 256^2 engine lacks).
template <int EPI, int OUTK, int CK, int SWIZ, int M, int N, int K, long AZ,
          long BZ, long CZ, long BRS>
__global__ __launch_bounds__(256, 4) void gemm_t(
    const ushort* __restrict__ A, const ushort* __restrict__ Bt,
    void* __restrict__ Cv, const int* __restrict__ flag,
    float* __restrict__ lsum, float scale0, float scale1) {
  __shared__ ushort lA[128 * 64];
  __shared__ ushort lB[128 * 64];
  __shared__ float lsh[(EPI == 2) ? 128 : 1];

  constexpr int MT = M / 128;
  const int nT = gridDim.x;
  const int id = blockIdx.y * nT + blockIdx.x;
  const int xcd = id & 7;
  const int loc = id >> 3;
  int nt, mt;
  if constexpr (SWIZ == 1) {
    const int ng = nT >> 3;
    nt = xcd * ng + loc % ng;
    mt = loc / ng;
  } else if constexpr (SWIZ == 2) {
    if (loc <= xcd) { mt = xcd; nt = loc; }
    else { mt = MT - 1 - xcd; nt = loc - xcd - 1; }
  } else if constexpr (SWIZ == 3) {
    nt = xcd;
    mt = loc;
  } else {
    nt = loc % nT;
    mt = xcd + ((loc / nT) << 3);
  }
  const int n0 = nt * 128;
  const int m0 = mt * 128;

  const int z = blockIdx.z;
  const ushort* Ab = A + (size_t)z * AZ;
  const ushort* Bb = Bt + (size_t)z * BZ;

  const int t = threadIdx.x;
  const int lane = t & 63;
  const int w = t >> 6;
  const int wm = (w >> 1) * 64;
  const int wn = (w & 1) * 64;
  const int quad = lane >> 4;
  const int l15 = lane & 15;

  if constexpr (EPI == 2) {
    if (t < 128) lsh[t] = 1.0f / lsum[(size_t)z * M + m0 + t];
  }

  f32x4 acc[4][4] = {};

  const int kEnd = CK ? ((m0 + 128 < K) ? (m0 + 128) : K) : K;

  for (int k0 = 0; k0 < kEnd; k0 += 64) {
    __syncthreads();
#pragma unroll
    for (int g0 = 0; g0 < 1024; g0 += 256) {
      const int g = g0 + t;
      const int r = g >> 3, c = (g & 7) << 3;
      async_copy16(Ab + (size_t)(m0 + r) * K + k0 + c, lA + g * 8);
    }
#pragma unroll
    for (int g0 = 0; g0 < 1024; g0 += 256) {
      const int g = g0 + t;
      const int r = g >> 3, c = (g & 7) << 3;
      async_copy16(Bb + (size_t)(n0 + r) * BRS + k0 + c, lB + g * 8);
    }
    __syncthreads();

#pragma unroll
    for (int h = 0; h < 2; h++) {
      bf16x8 af[4], bfr[4];
#pragma unroll
      for (int mi = 0; mi < 4; mi++)
        af[mi] = *(const bf16x8*)(lA + (wm + mi * 16 + l15) * 64 + h * 32 +
                                  quad * 8);
#pragma unroll
      for (int ni = 0; ni < 4; ni++)
        bfr[ni] = *(const bf16x8*)(lB + (wn + ni * 16 + l15) * 64 + h * 32 +
                                   quad * 8);
#pragma unroll
      for (int mi = 0; mi < 4; mi++)
#pragma unroll
        for (int ni = 0; ni < 4; ni++)
          acc[mi][ni] = __builtin_amdgcn_mfma_f32_16x16x32_bf16(
              af[mi], bfr[ni], acc[mi][ni], 0, 0, 0);
    }
  }

  const size_t zc = (size_t)z * CZ;

  if constexpr (EPI == 1) {
    ushort* C = (ushort*)Cv + zc;
    float* ls = lsum + (size_t)z * M;
#pragma unroll
    for (int mi = 0; mi < 4; mi++)
#pragma unroll
      for (int r = 0; r < 4; r++) {
        const int row = m0 + wm + mi * 16 + quad * 4 + r;
        float partial = 0.0f;
#pragma unroll
        for (int ni = 0; ni < 4; ni++) {
          const int col = n0 + wn + ni * 16 + l15;
          const float ev = (col <= row) ? __expf(acc[mi][ni][r]) : 0.0f;
          C[(size_t)row * N + col] = f2bf(ev);
          partial += ev;
        }
#pragma unroll
        for (int o = 1; o < 16; o <<= 1) partial += __shfl_xor(partial, o, 64);
        if (l15 == 0) atomicAdd(&ls[row], partial);
      }
    return;
  } else {
    const float scale = (z == 0) ? scale0 : scale1;
    const bool storeBf = (OUTK == 1) || (OUTK == 2 && *flag != 0);
#pragma unroll
    for (int mi = 0; mi < 4; mi++)
#pragma unroll
      for (int ni = 0; ni < 4; ni++)
#pragma unroll
        for (int r = 0; r < 4; r++) {
          const int lrow = wm + mi * 16 + quad * 4 + r;
          const int row = m0 + lrow;
          const int col = n0 + wn + ni * 16 + l15;
          const float sc = (EPI == 2) ? lsh[lrow] : scale;
          const float vv = acc[mi][ni][r] * sc;
          if (storeBf) {
            ushort* C = (ushort*)Cv + zc;
            C[(size_t)row * N + col] = f2bf(vv);
          } else {
            float* C = (float*)Cv + zc;
            C[(size_t)row * N + col] = vv;
          }
        }
  }
}

// Workspace (MB): 0 flag | 1 wt(6) | 7 xb(16) | 23 q(16) | 39 k(16) |
// 55 Vt_all [1024 x 8192] (16) | 71 E bf16(32) | 103 lsum(32KB)
extern "C" void kernel_launch(void* const* d_in, const int* in_sizes, int n_in,
                              void* d_out, int out_size, void* d_ws,
                              size_t ws_size, hipStream_t stream) {
  char* ws = (char*)d_ws;
  const size_t MB = 1024 * 1024;
  int* flag = (int*)ws;
  ushort* wt = (ushort*)(ws + 1 * MB);
  ushort* xb = (ushort*)(ws + 7 * MB);
  ushort* q = (ushort*)(ws + 23 * MB);
  ushort* vt = (ushort*)(ws + 55 * MB);
  ushort* sc = (ushort*)(ws + 71 * MB);
  float* lsum = (float*)(ws + 103 * MB);

  const void* x0 = d_in[0];
  const void* w0p = d_in[1];
  const void* w1p = d_in[2];
  const void* w2p = d_in[3];
  void* args[] = {(void*)&x0,  (void*)&w0p, (void*)&w1p, (void*)&w2p,
                  (void*)&xb,  (void*)&wt,  (void*)&flag, (void*)&lsum,
                  (void*)&q,   (void*)&sc,  (void*)&vt};
  hipLaunchCooperativeKernel(reinterpret_cast<void*>(fused), dim3(256),
                             dim3(512), args, 0, stream);

  // out = diag(1/l) * (E @ V^T); XCD owns n-tile (Vt slab L2-resident)
  gemm_t<2, 2, 1, 3, 2048, 1024, 2048, (long)SEQ * SEQ, 2048L,
         (long)SEQ * DIM, 8192L>
      <<<dim3(8, 16, 4), 256, 0, stream>>>(sc, vt, d_out, flag, lsum, 1.0f,
                                           1.0f);
}

// Round 8
// 238.067 us; speedup vs baseline: 2.1877x; 2.1877x over previous
//
#include <hip/hip_runtime.h>

#define SEQ 2048
#define DIM 1024

typedef __attribute__((ext_vector_type(8))) __bf16 bf16x8;
typedef __attribute__((ext_vector_type(4))) float f32x4;

typedef __attribute__((address_space(1))) unsigned char gu8_t;
typedef __attribute__((address_space(3))) unsigned char lu8_t;

__device__ __forceinline__ void async_copy16(const void* g, void* l) {
  __builtin_amdgcn_global_load_lds((gu8_t*)g, (lu8_t*)l, 16, 0, 0);
}

__device__ __forceinline__ ushort f2bf(float f) {
  union { float f; unsigned u; } v;
  v.f = f;
  unsigned r = v.u + 0x7FFFu + ((v.u >> 16) & 1u);
  return (ushort)(r >> 16);
}

// Merged prep (1288 blocks):
//   [0,512):     convert x -> bf16 xb, 8 chunks per block
//   [512,1280):  transpose the three weight matrices
//   [1280,1288): zero lsum (+ block 1280 publishes the dtype flag)
__global__ void prep(const void* __restrict__ xin, const void* __restrict__ w0,
                     const void* __restrict__ w1, const void* __restrict__ w2,
                     ushort* __restrict__ xb, ushort* __restrict__ wt,
                     int* __restrict__ flag, float* __restrict__ lsum) {
  __shared__ ushort tile[64][68];
  __shared__ int redi[4];
  const int bid = blockIdx.x;
  const int t = threadIdx.x;

  // local dtype detection (uniform across blocks), 1 sample word per thread
  const unsigned wv = ((const unsigned*)xin)[t];
  const unsigned b = (wv >> 8) & 0x7Fu;
  int hits = (b >= 0x3Bu && b <= 0x42u) ? 1 : 0;
#pragma unroll
  for (int o = 32; o > 0; o >>= 1) hits += __shfl_xor(hits, o, 64);
  if ((t & 63) == 0) redi[t >> 6] = hits;
  __syncthreads();
  const int bf = (redi[0] + redi[1] + redi[2] + redi[3] > 128) ? 1 : 0;

  if (bid >= 1280) {
    reinterpret_cast<float4*>(lsum)[(bid - 1280) * 256 + t] =
        make_float4(0.f, 0.f, 0.f, 0.f);
    if (bid == 1280 && t == 0) *flag = bf;
    return;
  }

  if (bid < 512) {
#pragma unroll
    for (int j = 0; j < 8; j++) {
      const int i = bid * 2048 + j * 256 + t;
      if (bf) {
        reinterpret_cast<uint4*>(xb)[i] =
            reinterpret_cast<const uint4*>(xin)[i];
      } else {
        const float4* f = reinterpret_cast<const float4*>(xin);
        const float4 a = f[2 * i], bb = f[2 * i + 1];
        ushort4 lo, hi;
        lo.x = f2bf(a.x); lo.y = f2bf(a.y); lo.z = f2bf(a.z); lo.w = f2bf(a.w);
        hi.x = f2bf(bb.x); hi.y = f2bf(bb.y); hi.z = f2bf(bb.z);
        hi.w = f2bf(bb.w);
        reinterpret_cast<ushort4*>(xb)[2 * i] = lo;
        reinterpret_cast<ushort4*>(xb)[2 * i + 1] = hi;
      }
    }
    return;
  }

  const int rem = bid - 512;
  const int z = rem >> 8;
  const int within = rem & 255;
  const int c0 = (within & 15) * 64, r0 = (within >> 4) * 64;
  const void* in = (z == 0) ? w0 : (z == 1) ? w1 : w2;
  ushort* op = wt + (size_t)z * 1024 * 1024;

  if (bf) {
    const ushort* ip = (const ushort*)in;
#pragma unroll
    for (int i = 0; i < 4; i++) {
      const int lin = i * 256 + t;
      const int r = lin >> 4, c4 = (lin & 15) << 2;
      const ushort4 v = *reinterpret_cast<const ushort4*>(
          ip + (size_t)(r0 + r) * 1024 + c0 + c4);
      tile[r][c4 + 0] = v.x; tile[r][c4 + 1] = v.y;
      tile[r][c4 + 2] = v.z; tile[r][c4 + 3] = v.w;
    }
  } else {
    const float* ip = (const float*)in;
#pragma unroll
    for (int i = 0; i < 4; i++) {
      const int lin = i * 256 + t;
      const int r = lin >> 4, c4 = (lin & 15) << 2;
      const float4 v = *reinterpret_cast<const float4*>(
          ip + (size_t)(r0 + r) * 1024 + c0 + c4);
      tile[r][c4 + 0] = f2bf(v.x); tile[r][c4 + 1] = f2bf(v.y);
      tile[r][c4 + 2] = f2bf(v.z); tile[r][c4 + 3] = f2bf(v.w);
    }
  }
  __syncthreads();
#pragma unroll
  for (int i = 0; i < 4; i++) {
    const int lin = i * 256 + t;
    const int c = lin >> 4, r4 = (lin & 15) << 2;
    ushort4 v;
    v.x = tile[r4 + 0][c]; v.y = tile[r4 + 1][c];
    v.z = tile[r4 + 2][c]; v.w = tile[r4 + 3][c];
    *reinterpret_cast<ushort4*>(op + (size_t)(c0 + c) * 1024 + r0 + r4) = v;
  }
}

// ============================================================================
// 256x256, BK=64, 8-wave (2Mx4N), 8-phase schedule with counted vmcnt.
// (EXACT R2/R6 engine -- proven: conflicts=0, VGPR 116, no spill, 69.7us VtE)
// MODE 0: proj Q,K. 256 blocks = exactly 1 round.
// MODE 1: merged Vt + E. id<144: E causal tri tile; id>=144: Vt tile.
// ============================================================================
template <int MODE>
__global__ __launch_bounds__(512, 2) void gemm8(
    const ushort* __restrict__ p0, const ushort* __restrict__ p1,
    const ushort* __restrict__ p2, void* __restrict__ c0,
    void* __restrict__ c1, float* __restrict__ lsum) {
  __shared__ ushort sA[2][2][128 * 64];
  __shared__ ushort sB[2][2][128 * 64];

  const ushort* A;
  const ushort* B;
  ushort* C;
  float* ls = nullptr;
  int m0, n0;
  long ldA, ldB, ldC;
  float scale = 1.0f;
  bool isE = false;

  const int id = blockIdx.x;
  if constexpr (MODE == 0) {
    const int z = id >> 7, r = id & 127;
    m0 = (r >> 2) << 8;
    n0 = (r & 3) << 8;
    A = p0; ldA = 1024;
    B = p1 + (size_t)z * 1024 * 1024; ldB = 1024;
    C = (ushort*)c0 + (size_t)z * 8192 * 1024; ldC = 1024;
    scale = z ? 1.0f : 0.03125f;
  } else {
    if (id < 144) {
      isE = true;
      const int z = id / 36;
      const int tri = id % 36;
      int mt = 0;
      while ((mt + 1) * (mt + 2) / 2 <= tri) mt++;
      const int nt = tri - mt * (mt + 1) / 2;
      m0 = mt << 8;
      n0 = nt << 8;
      A = p0 + (size_t)z * SEQ * DIM; ldA = 1024;
      B = p0 + (size_t)8192 * 1024 + (size_t)z * SEQ * DIM; ldB = 1024;
      C = (ushort*)c0 + (size_t)z * SEQ * SEQ; ldC = 2048;
      ls = lsum + (size_t)z * SEQ;
    } else {
      const int r = id - 144;
      m0 = (r >> 5) << 8;
      n0 = (r & 31) << 8;
      A = p1 + 2 * 1024 * 1024; ldA = 1024;
      B = p2; ldB = 1024;
      C = (ushort*)c1; ldC = 8192;
    }
  }
  constexpr int nT = 16;  // K = 1024 for all gemm8 users

  const int tid = threadIdx.x;
  const int lane = tid & 63;
  const int w = tid >> 6;        // 0..7
  const int quad = lane >> 4;    // 0..3
  const int l15 = lane & 15;
  const int ah = w >> 2;         // A half owned by this wave (row block of 128)
  const int wn = (w & 3) << 6;   // 0,64,128,192 within N-256
  const int bh = wn >> 7;        // B half
  const int bo = wn & 64;        // row offset within B half

  // Pre-swizzled global stage sources: LDS linear pos g holds global chunk
  // (g&7)^(row&7) of row g>>3.
  const ushort* aSrc[2][2];
  const ushort* bSrc[2][2];
#pragma unroll
  for (int h = 0; h < 2; h++)
#pragma unroll
    for (int i = 0; i < 2; i++) {
      const int g = i * 512 + tid;
      const int rl = g >> 3;
      const int ck = (g & 7) ^ (rl & 7);
      aSrc[h][i] = A + (size_t)(m0 + h * 128 + rl) * ldA + ck * 8;
      bSrc[h][i] = B + (size_t)(n0 + h * 128 + rl) * ldB + ck * 8;
    }

  auto stageA = [&](int t, int b) {
#pragma unroll
    for (int h = 0; h < 2; h++)
#pragma unroll
      for (int i = 0; i < 2; i++)
        async_copy16(aSrc[h][i] + t * 64, &sA[b][h][(i * 512 + tid) * 8]);
  };
  auto stageB = [&](int t, int b) {
#pragma unroll
    for (int h = 0; h < 2; h++)
#pragma unroll
      for (int i = 0; i < 2; i++)
        async_copy16(bSrc[h][i] + t * 64, &sB[b][h][(i * 512 + tid) * 8]);
  };
  auto rdA = [&](int b, int rbase, int kh) -> bf16x8 {
    const int row = rbase + l15;
    const int ck = ((kh << 2) | quad) ^ (row & 7);
    return *(const bf16x8*)&sA[b][ah][row * 64 + ck * 8];
  };
  auto rdB = [&](int b, int rbase, int kh) -> bf16x8 {
    const int row = rbase + l15;
    const int ck = ((kh << 2) | quad) ^ (row & 7);
    return *(const bf16x8*)&sB[b][bh][row * 64 + ck * 8];
  };

  f32x4 acc[8][4] = {};
  bf16x8 aF[8], bF0[4], bF1[4];

  // Prologue: tiles 0 and 1 in flight; wait for tile 0 (8 newest stay out).
  stageA(0, 0); stageB(0, 0);
  stageA(1, 1); stageB(1, 1);
  asm volatile("s_waitcnt vmcnt(8)" ::: "memory");
  __builtin_amdgcn_s_barrier();

#pragma unroll 1
  for (int t = 0; t < nT; t++) {
    const int b = t & 1;

    // --- phase 1 ---
#pragma unroll
    for (int m = 0; m < 4; m++)
#pragma unroll
      for (int h = 0; h < 2; h++) aF[m * 2 + h] = rdA(b, m * 16, h);
#pragma unroll
    for (int n = 0; n < 2; n++)
#pragma unroll
      for (int h = 0; h < 2; h++) bF0[n * 2 + h] = rdB(b, bo + n * 16, h);
    __builtin_amdgcn_s_barrier();
    __builtin_amdgcn_s_setprio(1);
#pragma unroll
    for (int h = 0; h < 2; h++)
#pragma unroll
      for (int m = 0; m < 4; m++)
#pragma unroll
        for (int n = 0; n < 2; n++)
          acc[m][n] = __builtin_amdgcn_mfma_f32_16x16x32_bf16(
              aF[m * 2 + h], bF0[n * 2 + h], acc[m][n], 0, 0, 0);
    __builtin_amdgcn_s_setprio(0);
    __builtin_amdgcn_s_barrier();

    // --- phase 2 ---
#pragma unroll
    for (int n = 0; n < 2; n++)
#pragma unroll
      for (int h = 0; h < 2; h++)
        bF1[n * 2 + h] = rdB(b, bo + 32 + n * 16, h);
    __builtin_amdgcn_s_barrier();
    __builtin_amdgcn_s_setprio(1);
#pragma unroll
    for (int h = 0; h < 2; h++)
#pragma unroll
      for (int m = 0; m < 4; m++)
#pragma unroll
        for (int n = 0; n < 2; n++)
          acc[m][2 + n] = __builtin_amdgcn_mfma_f32_16x16x32_bf16(
              aF[m * 2 + h], bF1[n * 2 + h], acc[m][2 + n], 0, 0, 0);
    __builtin_amdgcn_s_setprio(0);
    __builtin_amdgcn_s_barrier();

    // --- phase 3 --- (B regions of buf b fully consumed -> safe to overwrite)
#pragma unroll
    for (int m = 0; m < 4; m++)
#pragma unroll
      for (int h = 0; h < 2; h++) aF[m * 2 + h] = rdA(b, 64 + m * 16, h);
    if (t + 2 < nT) stageB(t + 2, b);
    __builtin_amdgcn_s_barrier();
    __builtin_amdgcn_s_setprio(1);
#pragma unroll
    for (int h = 0; h < 2; h++)
#pragma unroll
      for (int m = 0; m < 4; m++)
#pragma unroll
        for (int n = 0; n < 2; n++)
          acc[4 + m][n] = __builtin_amdgcn_mfma_f32_16x16x32_bf16(
              aF[m * 2 + h], bF0[n * 2 + h], acc[4 + m][n], 0, 0, 0);
    __builtin_amdgcn_s_setprio(0);
    __builtin_amdgcn_s_barrier();

    // --- phase 4 --- (A regions fully consumed -> safe to overwrite)
    if (t + 2 < nT) stageA(t + 2, b);
    __builtin_amdgcn_s_setprio(1);
#pragma unroll
    for (int h = 0; h < 2; h++)
#pragma unroll
      for (int m = 0; m < 4; m++)
#pragma unroll
        for (int n = 0; n < 2; n++)
          acc[4 + m][2 + n] = __builtin_amdgcn_mfma_f32_16x16x32_bf16(
              aF[m * 2 + h], bF1[n * 2 + h], acc[4 + m][2 + n], 0, 0, 0);
    __builtin_amdgcn_s_setprio(0);
    if (t + 2 < nT)
      asm volatile("s_waitcnt vmcnt(8)" ::: "memory");  // tile t+1 landed
    else
      asm volatile("s_waitcnt vmcnt(0)" ::: "memory");  // drain tail
    __builtin_amdgcn_s_barrier();
  }

  if (MODE == 1 && isE) {
#pragma unroll
    for (int mi = 0; mi < 8; mi++)
#pragma unroll
      for (int r = 0; r < 4; r++) {
        const int row = m0 + ah * 128 + mi * 16 + quad * 4 + r;
        float partial = 0.0f;
#pragma unroll
        for (int ni = 0; ni < 4; ni++) {
          const int col = n0 + wn + ni * 16 + l15;
          const float ev = (col <= row) ? __expf(acc[mi][ni][r]) : 0.0f;
          C[(size_t)row * ldC + col] = f2bf(ev);
          partial += ev;
        }
#pragma unroll
        for (int o = 1; o < 16; o <<= 1) partial += __shfl_xor(partial, o, 64);
        if (l15 == 0) atomicAdd(&ls[row], partial);
      }
  } else {
#pragma unroll
    for (int mi = 0; mi < 8; mi++)
#pragma unroll
      for (int ni = 0; ni < 4; ni++)
#pragma unroll
        for (int r = 0; r < 4; r++) {
          const int row = m0 + ah * 128 + mi * 16 + quad * 4 + r;
          const int col = n0 + wn + ni * 16 + l15;
          C[(size_t)row * ldC + col] = f2bf(acc[mi][ni][r] * scale);
        }
  }
}

// Old 128x128 engine, kept for PV only (causal K-truncation load balance).
// SWIZ 4 (new): nt = xcd, mt = loc, with mt -> MT-1-mt for z>=2. Pairs deep
// tiles (K-steps 2(mt+1)) with shallow ones on the same CU across the two
// dispatch rounds: per-CU K-steps 2(loc+1)+2(16-loc) = 34 for every CU
// (was 4(loc+1), max 64) -- pure tile remap, no sync/addressing change.
template <int EPI, int OUTK, int CK, int SWIZ, int M, int N, int K, long AZ,
          long BZ, long CZ, long BRS>
__global__ __launch_bounds__(256, 4) void gemm_t(
    const ushort* __restrict__ A, const ushort* __restrict__ Bt,
    void* __restrict__ Cv, const int* __restrict__ flag,
    float* __restrict__ lsum, float scale0, float scale1) {
  __shared__ ushort lA[128 * 64];
  __shared__ ushort lB[128 * 64];
  __shared__ float lsh[(EPI == 2) ? 128 : 1];

  constexpr int MT = M / 128;
  const int nT = gridDim.x;
  const int id = blockIdx.y * nT + blockIdx.x;
  const int xcd = id & 7;
  const int loc = id >> 3;
  int nt, mt;
  if constexpr (SWIZ == 1) {
    const int ng = nT >> 3;
    nt = xcd * ng + loc % ng;
    mt = loc / ng;
  } else if constexpr (SWIZ == 2) {
    if (loc <= xcd) { mt = xcd; nt = loc; }
    else { mt = MT - 1 - xcd; nt = loc - xcd - 1; }
  } else if constexpr (SWIZ == 3) {
    nt = xcd;
    mt = loc;
  } else if constexpr (SWIZ == 4) {
    nt = xcd;
    mt = (blockIdx.z >= 2) ? (MT - 1 - loc) : loc;
  } else {
    nt = loc % nT;
    mt = xcd + ((loc / nT) << 3);
  }
  const int n0 = nt * 128;
  const int m0 = mt * 128;

  const int z = blockIdx.z;
  const ushort* Ab = A + (size_t)z * AZ;
  const ushort* Bb = Bt + (size_t)z * BZ;

  const int t = threadIdx.x;
  const int lane = t & 63;
  const int w = t >> 6;
  const int wm = (w >> 1) * 64;
  const int wn = (w & 1) * 64;
  const int quad = lane >> 4;
  const int l15 = lane & 15;

  if constexpr (EPI == 2) {
    if (t < 128) lsh[t] = 1.0f / lsum[(size_t)z * M + m0 + t];
  }

  f32x4 acc[4][4] = {};

  const int kEnd = CK ? ((m0 + 128 < K) ? (m0 + 128) : K) : K;

  for (int k0 = 0; k0 < kEnd; k0 += 64) {
    __syncthreads();
#pragma unroll
    for (int g0 = 0; g0 < 1024; g0 += 256) {
      const int g = g0 + t;
      const int r = g >> 3, c = (g & 7) << 3;
      async_copy16(Ab + (size_t)(m0 + r) * K + k0 + c, lA + g * 8);
    }
#pragma unroll
    for (int g0 = 0; g0 < 1024; g0 += 256) {
      const int g = g0 + t;
      const int r = g >> 3, c = (g & 7) << 3;
      async_copy16(Bb + (size_t)(n0 + r) * BRS + k0 + c, lB + g * 8);
    }
    __syncthreads();

#pragma unroll
    for (int h = 0; h < 2; h++) {
      bf16x8 af[4], bfr[4];
#pragma unroll
      for (int mi = 0; mi < 4; mi++)
        af[mi] = *(const bf16x8*)(lA + (wm + mi * 16 + l15) * 64 + h * 32 +
                                  quad * 8);
#pragma unroll
      for (int ni = 0; ni < 4; ni++)
        bfr[ni] = *(const bf16x8*)(lB + (wn + ni * 16 + l15) * 64 + h * 32 +
                                   quad * 8);
#pragma unroll
      for (int mi = 0; mi < 4; mi++)
#pragma unroll
        for (int ni = 0; ni < 4; ni++)
          acc[mi][ni] = __builtin_amdgcn_mfma_f32_16x16x32_bf16(
              af[mi], bfr[ni], acc[mi][ni], 0, 0, 0);
    }
  }

  const size_t zc = (size_t)z * CZ;

  if constexpr (EPI == 1) {
    ushort* C = (ushort*)Cv + zc;
    float* ls = lsum + (size_t)z * M;
#pragma unroll
    for (int mi = 0; mi < 4; mi++)
#pragma unroll
      for (int r = 0; r < 4; r++) {
        const int row = m0 + wm + mi * 16 + quad * 4 + r;
        float partial = 0.0f;
#pragma unroll
        for (int ni = 0; ni < 4; ni++) {
          const int col = n0 + wn + ni * 16 + l15;
          const float ev = (col <= row) ? __expf(acc[mi][ni][r]) : 0.0f;
          C[(size_t)row * N + col] = f2bf(ev);
          partial += ev;
        }
#pragma unroll
        for (int o = 1; o < 16; o <<= 1) partial += __shfl_xor(partial, o, 64);
        if (l15 == 0) atomicAdd(&ls[row], partial);
      }
    return;
  } else {
    const float scale = (z == 0) ? scale0 : scale1;
    const bool storeBf = (OUTK == 1) || (OUTK == 2 && *flag != 0);
#pragma unroll
    for (int mi = 0; mi < 4; mi++)
#pragma unroll
      for (int ni = 0; ni < 4; ni++)
#pragma unroll
        for (int r = 0; r < 4; r++) {
          const int lrow = wm + mi * 16 + quad * 4 + r;
          const int row = m0 + lrow;
          const int col = n0 + wn + ni * 16 + l15;
          const float sc = (EPI == 2) ? lsh[lrow] : scale;
          const float vv = acc[mi][ni][r] * sc;
          if (storeBf) {
            ushort* C = (ushort*)Cv + zc;
            C[(size_t)row * N + col] = f2bf(vv);
          } else {
            float* C = (float*)Cv + zc;
            C[(size_t)row * N + col] = vv;
          }
        }
  }
}

// Workspace (MB): 0 flag | 1 wt(6) | 7 xb(16) | 23 q(16) | 39 k(16) |
// 55 Vt_all [1024 x 8192] (16) | 71 E bf16(32) | 103 lsum(32KB)
extern "C" void kernel_launch(void* const* d_in, const int* in_sizes, int n_in,
                              void* d_out, int out_size, void* d_ws,
                              size_t ws_size, hipStream_t stream) {
  char* ws = (char*)d_ws;
  const size_t MB = 1024 * 1024;
  int* flag = (int*)ws;
  ushort* wt = (ushort*)(ws + 1 * MB);
  ushort* xb = (ushort*)(ws + 7 * MB);
  ushort* q = (ushort*)(ws + 23 * MB);
  ushort* vt = (ushort*)(ws + 55 * MB);
  ushort* sc = (ushort*)(ws + 71 * MB);
  float* lsum = (float*)(ws + 103 * MB);

  prep<<<dim3(1288), 256, 0, stream>>>(d_in[0], d_in[1], d_in[2], d_in[3], xb,
                                       wt, flag, lsum);

  // Q,K projections: exactly 256 blocks = 1 clean round (1 block/CU).
  gemm8<0><<<dim3(256), 512, 0, stream>>>(xb, wt, nullptr, (void*)q, nullptr,
                                          nullptr);

  // Merged: blocks [0,144) -> E = exp(Q K^T) causal (exact tri list) + lsum;
  //         blocks [144,272) -> Vt = Wv^T X^T [1024x8192].
  gemm8<1><<<dim3(272), 512, 0, stream>>>(q, wt, xb, (void*)sc, (void*)vt,
                                          lsum);

  // out = diag(1/l) * (E @ V^T); SWIZ 4: XCD owns n-tile + balanced mt
  // pairing across z-halves (per-CU K-steps 34, was up to 64).
  gemm_t<2, 2, 1, 4, 2048, 1024, 2048, (long)SEQ * SEQ, 2048L,
         (long)SEQ * DIM, 8192L>
      <<<dim3(8, 16, 4), 256, 0, stream>>>(sc, vt, d_out, flag, lsum, 1.0f,
                                           1.0f);
}

// Round 9
// 230.733 us; speedup vs baseline: 2.2572x; 1.0318x over previous
//
#include <hip/hip_runtime.h>

#define SEQ 2048
#define DIM 1024

typedef __attribute__((ext_vector_type(8))) __bf16 bf16x8;
typedef __attribute__((ext_vector_type(4))) float f32x4;

typedef __attribute__((address_space(1))) unsigned char gu8_t;
typedef __attribute__((address_space(3))) unsigned char lu8_t;

__device__ __forceinline__ void async_copy16(const void* g, void* l) {
  __builtin_amdgcn_global_load_lds((gu8_t*)g, (lu8_t*)l, 16, 0, 0);
}

__device__ __forceinline__ ushort f2bf(float f) {
  union { float f; unsigned u; } v;
  v.f = f;
  unsigned r = v.u + 0x7FFFu + ((v.u >> 16) & 1u);
  return (ushort)(r >> 16);
}

// Merged prep (1288 blocks):
//   [0,512):     convert x -> bf16 xb, 8 chunks per block
//   [512,1280):  transpose the three weight matrices
//   [1280,1288): zero lsum (+ block 1280 publishes the dtype flag)
__global__ void prep(const void* __restrict__ xin, const void* __restrict__ w0,
                     const void* __restrict__ w1, const void* __restrict__ w2,
                     ushort* __restrict__ xb, ushort* __restrict__ wt,
                     int* __restrict__ flag, float* __restrict__ lsum) {
  __shared__ ushort tile[64][68];
  __shared__ int redi[4];
  const int bid = blockIdx.x;
  const int t = threadIdx.x;

  // local dtype detection (uniform across blocks), 1 sample word per thread
  const unsigned wv = ((const unsigned*)xin)[t];
  const unsigned b = (wv >> 8) & 0x7Fu;
  int hits = (b >= 0x3Bu && b <= 0x42u) ? 1 : 0;
#pragma unroll
  for (int o = 32; o > 0; o >>= 1) hits += __shfl_xor(hits, o, 64);
  if ((t & 63) == 0) redi[t >> 6] = hits;
  __syncthreads();
  const int bf = (redi[0] + redi[1] + redi[2] + redi[3] > 128) ? 1 : 0;

  if (bid >= 1280) {
    reinterpret_cast<float4*>(lsum)[(bid - 1280) * 256 + t] =
        make_float4(0.f, 0.f, 0.f, 0.f);
    if (bid == 1280 && t == 0) *flag = bf;
    return;
  }

  if (bid < 512) {
#pragma unroll
    for (int j = 0; j < 8; j++) {
      const int i = bid * 2048 + j * 256 + t;
      if (bf) {
        reinterpret_cast<uint4*>(xb)[i] =
            reinterpret_cast<const uint4*>(xin)[i];
      } else {
        const float4* f = reinterpret_cast<const float4*>(xin);
        const float4 a = f[2 * i], bb = f[2 * i + 1];
        ushort4 lo, hi;
        lo.x = f2bf(a.x); lo.y = f2bf(a.y); lo.z = f2bf(a.z); lo.w = f2bf(a.w);
        hi.x = f2bf(bb.x); hi.y = f2bf(bb.y); hi.z = f2bf(bb.z);
        hi.w = f2bf(bb.w);
        reinterpret_cast<ushort4*>(xb)[2 * i] = lo;
        reinterpret_cast<ushort4*>(xb)[2 * i + 1] = hi;
      }
    }
    return;
  }

  const int rem = bid - 512;
  const int z = rem >> 8;
  const int within = rem & 255;
  const int c0 = (within & 15) * 64, r0 = (within >> 4) * 64;
  const void* in = (z == 0) ? w0 : (z == 1) ? w1 : w2;
  ushort* op = wt + (size_t)z * 1024 * 1024;

  if (bf) {
    const ushort* ip = (const ushort*)in;
#pragma unroll
    for (int i = 0; i < 4; i++) {
      const int lin = i * 256 + t;
      const int r = lin >> 4, c4 = (lin & 15) << 2;
      const ushort4 v = *reinterpret_cast<const ushort4*>(
          ip + (size_t)(r0 + r) * 1024 + c0 + c4);
      tile[r][c4 + 0] = v.x; tile[r][c4 + 1] = v.y;
      tile[r][c4 + 2] = v.z; tile[r][c4 + 3] = v.w;
    }
  } else {
    const float* ip = (const float*)in;
#pragma unroll
    for (int i = 0; i < 4; i++) {
      const int lin = i * 256 + t;
      const int r = lin >> 4, c4 = (lin & 15) << 2;
      const float4 v = *reinterpret_cast<const float4*>(
          ip + (size_t)(r0 + r) * 1024 + c0 + c4);
      tile[r][c4 + 0] = f2bf(v.x); tile[r][c4 + 1] = f2bf(v.y);
      tile[r][c4 + 2] = f2bf(v.z); tile[r][c4 + 3] = f2bf(v.w);
    }
  }
  __syncthreads();
#pragma unroll
  for (int i = 0; i < 4; i++) {
    const int lin = i * 256 + t;
    const int c = lin >> 4, r4 = (lin & 15) << 2;
    ushort4 v;
    v.x = tile[r4 + 0][c]; v.y = tile[r4 + 1][c];
    v.z = tile[r4 + 2][c]; v.w = tile[r4 + 3][c];
    *reinterpret_cast<ushort4*>(op + (size_t)(c0 + c) * 1024 + r0 + r4) = v;
  }
}

// ============================================================================
// 256x256, BK=64, 8-wave (2Mx4N), 8-phase schedule with counted vmcnt.
// (EXACT R2/R6 engine -- proven: conflicts=0, VGPR 116, no spill, 69.7us VtE)
// MODE 0: proj Q,K. 256 blocks = exactly 1 round.
// MODE 1: merged Vt + E. id<144: E causal tri tile; id>=144: Vt tile.
// ============================================================================
template <int MODE>
__global__ __launch_bounds__(512, 2) void gemm8(
    const ushort* __restrict__ p0, const ushort* __restrict__ p1,
    const ushort* __restrict__ p2, void* __restrict__ c0,
    void* __restrict__ c1, float* __restrict__ lsum) {
  __shared__ ushort sA[2][2][128 * 64];
  __shared__ ushort sB[2][2][128 * 64];

  const ushort* A;
  const ushort* B;
  ushort* C;
  float* ls = nullptr;
  int m0, n0;
  long ldA, ldB, ldC;
  float scale = 1.0f;
  bool isE = false;

  const int id = blockIdx.x;
  if constexpr (MODE == 0) {
    const int z = id >> 7, r = id & 127;
    m0 = (r >> 2) << 8;
    n0 = (r & 3) << 8;
    A = p0; ldA = 1024;
    B = p1 + (size_t)z * 1024 * 1024; ldB = 1024;
    C = (ushort*)c0 + (size_t)z * 8192 * 1024; ldC = 1024;
    scale = z ? 1.0f : 0.03125f;
  } else {
    if (id < 144) {
      isE = true;
      const int z = id / 36;
      const int tri = id % 36;
      int mt = 0;
      while ((mt + 1) * (mt + 2) / 2 <= tri) mt++;
      const int nt = tri - mt * (mt + 1) / 2;
      m0 = mt << 8;
      n0 = nt << 8;
      A = p0 + (size_t)z * SEQ * DIM; ldA = 1024;
      B = p0 + (size_t)8192 * 1024 + (size_t)z * SEQ * DIM; ldB = 1024;
      C = (ushort*)c0 + (size_t)z * SEQ * SEQ; ldC = 2048;
      ls = lsum + (size_t)z * SEQ;
    } else {
      const int r = id - 144;
      m0 = (r >> 5) << 8;
      n0 = (r & 31) << 8;
      A = p1 + 2 * 1024 * 1024; ldA = 1024;
      B = p2; ldB = 1024;
      C = (ushort*)c1; ldC = 8192;
    }
  }
  constexpr int nT = 16;  // K = 1024 for all gemm8 users

  const int tid = threadIdx.x;
  const int lane = tid & 63;
  const int w = tid >> 6;        // 0..7
  const int quad = lane >> 4;    // 0..3
  const int l15 = lane & 15;
  const int ah = w >> 2;         // A half owned by this wave (row block of 128)
  const int wn = (w & 3) << 6;   // 0,64,128,192 within N-256
  const int bh = wn >> 7;        // B half
  const int bo = wn & 64;        // row offset within B half

  // Pre-swizzled global stage sources: LDS linear pos g holds global chunk
  // (g&7)^(row&7) of row g>>3.
  const ushort* aSrc[2][2];
  const ushort* bSrc[2][2];
#pragma unroll
  for (int h = 0; h < 2; h++)
#pragma unroll
    for (int i = 0; i < 2; i++) {
      const int g = i * 512 + tid;
      const int rl = g >> 3;
      const int ck = (g & 7) ^ (rl & 7);
      aSrc[h][i] = A + (size_t)(m0 + h * 128 + rl) * ldA + ck * 8;
      bSrc[h][i] = B + (size_t)(n0 + h * 128 + rl) * ldB + ck * 8;
    }

  auto stageA = [&](int t, int b) {
#pragma unroll
    for (int h = 0; h < 2; h++)
#pragma unroll
      for (int i = 0; i < 2; i++)
        async_copy16(aSrc[h][i] + t * 64, &sA[b][h][(i * 512 + tid) * 8]);
  };
  auto stageB = [&](int t, int b) {
#pragma unroll
    for (int h = 0; h < 2; h++)
#pragma unroll
      for (int i = 0; i < 2; i++)
        async_copy16(bSrc[h][i] + t * 64, &sB[b][h][(i * 512 + tid) * 8]);
  };
  auto rdA = [&](int b, int rbase, int kh) -> bf16x8 {
    const int row = rbase + l15;
    const int ck = ((kh << 2) | quad) ^ (row & 7);
    return *(const bf16x8*)&sA[b][ah][row * 64 + ck * 8];
  };
  auto rdB = [&](int b, int rbase, int kh) -> bf16x8 {
    const int row = rbase + l15;
    const int ck = ((kh << 2) | quad) ^ (row & 7);
    return *(const bf16x8*)&sB[b][bh][row * 64 + ck * 8];
  };

  f32x4 acc[8][4] = {};
  bf16x8 aF[8], bF0[4], bF1[4];

  // Prologue: tiles 0 and 1 in flight; wait for tile 0 (8 newest stay out).
  stageA(0, 0); stageB(0, 0);
  stageA(1, 1); stageB(1, 1);
  asm volatile("s_waitcnt vmcnt(8)" ::: "memory");
  __builtin_amdgcn_s_barrier();

#pragma unroll 1
  for (int t = 0; t < nT; t++) {
    const int b = t & 1;

    // --- phase 1 ---
#pragma unroll
    for (int m = 0; m < 4; m++)
#pragma unroll
      for (int h = 0; h < 2; h++) aF[m * 2 + h] = rdA(b, m * 16, h);
#pragma unroll
    for (int n = 0; n < 2; n++)
#pragma unroll
      for (int h = 0; h < 2; h++) bF0[n * 2 + h] = rdB(b, bo + n * 16, h);
    __builtin_amdgcn_s_barrier();
    __builtin_amdgcn_s_setprio(1);
#pragma unroll
    for (int h = 0; h < 2; h++)
#pragma unroll
      for (int m = 0; m < 4; m++)
#pragma unroll
        for (int n = 0; n < 2; n++)
          acc[m][n] = __builtin_amdgcn_mfma_f32_16x16x32_bf16(
              aF[m * 2 + h], bF0[n * 2 + h], acc[m][n], 0, 0, 0);
    __builtin_amdgcn_s_setprio(0);
    __builtin_amdgcn_s_barrier();

    // --- phase 2 ---
#pragma unroll
    for (int n = 0; n < 2; n++)
#pragma unroll
      for (int h = 0; h < 2; h++)
        bF1[n * 2 + h] = rdB(b, bo + 32 + n * 16, h);
    __builtin_amdgcn_s_barrier();
    __builtin_amdgcn_s_setprio(1);
#pragma unroll
    for (int h = 0; h < 2; h++)
#pragma unroll
      for (int m = 0; m < 4; m++)
#pragma unroll
        for (int n = 0; n < 2; n++)
          acc[m][2 + n] = __builtin_amdgcn_mfma_f32_16x16x32_bf16(
              aF[m * 2 + h], bF1[n * 2 + h], acc[m][2 + n], 0, 0, 0);
    __builtin_amdgcn_s_setprio(0);
    __builtin_amdgcn_s_barrier();

    // --- phase 3 --- (B regions of buf b fully consumed -> safe to overwrite)
#pragma unroll
    for (int m = 0; m < 4; m++)
#pragma unroll
      for (int h = 0; h < 2; h++) aF[m * 2 + h] = rdA(b, 64 + m * 16, h);
    if (t + 2 < nT) stageB(t + 2, b);
    __builtin_amdgcn_s_barrier();
    __builtin_amdgcn_s_setprio(1);
#pragma unroll
    for (int h = 0; h < 2; h++)
#pragma unroll
      for (int m = 0; m < 4; m++)
#pragma unroll
        for (int n = 0; n < 2; n++)
          acc[4 + m][n] = __builtin_amdgcn_mfma_f32_16x16x32_bf16(
              aF[m * 2 + h], bF0[n * 2 + h], acc[4 + m][n], 0, 0, 0);
    __builtin_amdgcn_s_setprio(0);
    __builtin_amdgcn_s_barrier();

    // --- phase 4 --- (A regions fully consumed -> safe to overwrite)
    if (t + 2 < nT) stageA(t + 2, b);
    __builtin_amdgcn_s_setprio(1);
#pragma unroll
    for (int h = 0; h < 2; h++)
#pragma unroll
      for (int m = 0; m < 4; m++)
#pragma unroll
        for (int n = 0; n < 2; n++)
          acc[4 + m][2 + n] = __builtin_amdgcn_mfma_f32_16x16x32_bf16(
              aF[m * 2 + h], bF1[n * 2 + h], acc[4 + m][2 + n], 0, 0, 0);
    __builtin_amdgcn_s_setprio(0);
    if (t + 2 < nT)
      asm volatile("s_waitcnt vmcnt(8)" ::: "memory");  // tile t+1 landed
    else
      asm volatile("s_waitcnt vmcnt(0)" ::: "memory");  // drain tail
    __builtin_amdgcn_s_barrier();
  }

  if (MODE == 1 && isE) {
#pragma unroll
    for (int mi = 0; mi < 8; mi++)
#pragma unroll
      for (int r = 0; r < 4; r++) {
        const int row = m0 + ah * 128 + mi * 16 + quad * 4 + r;
        float partial = 0.0f;
#pragma unroll
        for (int ni = 0; ni < 4; ni++) {
          const int col = n0 + wn + ni * 16 + l15;
          const float ev = (col <= row) ? __expf(acc[mi][ni][r]) : 0.0f;
          C[(size_t)row * ldC + col] = f2bf(ev);
          partial += ev;
        }
#pragma unroll
        for (int o = 1; o < 16; o <<= 1) partial += __shfl_xor(partial, o, 64);
        if (l15 == 0) atomicAdd(&ls[row], partial);
      }
  } else {
#pragma unroll
    for (int mi = 0; mi < 8; mi++)
#pragma unroll
      for (int ni = 0; ni < 4; ni++)
#pragma unroll
        for (int r = 0; r < 4; r++) {
          const int row = m0 + ah * 128 + mi * 16 + quad * 4 + r;
          const int col = n0 + wn + ni * 16 + l15;
          C[(size_t)row * ldC + col] = f2bf(acc[mi][ni][r] * scale);
        }
  }
}

// 128xBN engine, PV only. BN=64 + SWIZ 5: grid (16,16,4), 1024 blocks at
// 4 blocks/CU (LDS 24.5KB). nt = x (vt slab per XCD L2-resident: all y of
// same (x,z) land on one XCD). mt = y flipped for z>=2: the 4 co-resident
// blocks of a CU (z=0..3 of same x,y) total 2[(y+1)+(16-y)] = 34 K-steps
// uniformly, and 4-deep co-residency overlaps their pipeline stalls.
template <int EPI, int OUTK, int CK, int SWIZ, int M, int N, int K, long AZ,
          long BZ, long CZ, long BRS, int BN = 128>
__global__ __launch_bounds__(256, 4) void gemm_t(
    const ushort* __restrict__ A, const ushort* __restrict__ Bt,
    void* __restrict__ Cv, const int* __restrict__ flag,
    float* __restrict__ lsum, float scale0, float scale1) {
  __shared__ ushort lA[128 * 64];
  __shared__ ushort lB[BN * 64];
  __shared__ float lsh[(EPI == 2) ? 128 : 1];

  constexpr int MT = M / 128;
  constexpr int MI = (BN == 128) ? 4 : 2;  // 16-row A-frags per wave
  const int nT = gridDim.x;
  const int id = blockIdx.y * nT + blockIdx.x;
  const int xcd = id & 7;
  const int loc = id >> 3;
  const int z = blockIdx.z;
  int nt, mt;
  if constexpr (SWIZ == 1) {
    const int ng = nT >> 3;
    nt = xcd * ng + loc % ng;
    mt = loc / ng;
  } else if constexpr (SWIZ == 2) {
    if (loc <= xcd) { mt = xcd; nt = loc; }
    else { mt = MT - 1 - xcd; nt = loc - xcd - 1; }
  } else if constexpr (SWIZ == 3) {
    nt = xcd;
    mt = loc;
  } else if constexpr (SWIZ == 4) {
    nt = xcd;
    mt = (z >= 2) ? (MT - 1 - loc) : loc;
  } else if constexpr (SWIZ == 5) {
    nt = blockIdx.x;
    mt = (z >= 2) ? (MT - 1 - blockIdx.y) : blockIdx.y;
  } else {
    nt = loc % nT;
    mt = xcd + ((loc / nT) << 3);
  }
  const int n0 = nt * BN;
  const int m0 = mt * 128;

  const ushort* Ab = A + (size_t)z * AZ;
  const ushort* Bb = Bt + (size_t)z * BZ;

  const int t = threadIdx.x;
  const int lane = t & 63;
  const int w = t >> 6;
  const int wm = (BN == 128) ? ((w >> 1) * 64) : (w * 32);
  const int wn = (BN == 128) ? ((w & 1) * 64) : 0;
  const int quad = lane >> 4;
  const int l15 = lane & 15;

  if constexpr (EPI == 2) {
    if (t < 128) lsh[t] = 1.0f / lsum[(size_t)z * M + m0 + t];
  }

  f32x4 acc[MI][4] = {};

  const int kEnd = CK ? ((m0 + 128 < K) ? (m0 + 128) : K) : K;

  for (int k0 = 0; k0 < kEnd; k0 += 64) {
    __syncthreads();
#pragma unroll
    for (int g0 = 0; g0 < 1024; g0 += 256) {
      const int g = g0 + t;
      const int r = g >> 3, c = (g & 7) << 3;
      async_copy16(Ab + (size_t)(m0 + r) * K + k0 + c, lA + g * 8);
    }
#pragma unroll
    for (int g0 = 0; g0 < BN * 8; g0 += 256) {
      const int g = g0 + t;
      const int r = g >> 3, c = (g & 7) << 3;
      async_copy16(Bb + (size_t)(n0 + r) * BRS + k0 + c, lB + g * 8);
    }
    __syncthreads();

#pragma unroll
    for (int h = 0; h < 2; h++) {
      bf16x8 af[MI], bfr[4];
#pragma unroll
      for (int mi = 0; mi < MI; mi++)
        af[mi] = *(const bf16x8*)(lA + (wm + mi * 16 + l15) * 64 + h * 32 +
                                  quad * 8);
#pragma unroll
      for (int ni = 0; ni < 4; ni++)
        bfr[ni] = *(const bf16x8*)(lB + (wn + ni * 16 + l15) * 64 + h * 32 +
                                   quad * 8);
#pragma unroll
      for (int mi = 0; mi < MI; mi++)
#pragma unroll
        for (int ni = 0; ni < 4; ni++)
          acc[mi][ni] = __builtin_amdgcn_mfma_f32_16x16x32_bf16(
              af[mi], bfr[ni], acc[mi][ni], 0, 0, 0);
    }
  }

  const size_t zc = (size_t)z * CZ;

  if constexpr (EPI == 1) {
    ushort* C = (ushort*)Cv + zc;
    float* ls = lsum + (size_t)z * M;
#pragma unroll
    for (int mi = 0; mi < MI; mi++)
#pragma unroll
      for (int r = 0; r < 4; r++) {
        const int row = m0 + wm + mi * 16 + quad * 4 + r;
        float partial = 0.0f;
#pragma unroll
        for (int ni = 0; ni < 4; ni++) {
          const int col = n0 + wn + ni * 16 + l15;
          const float ev = (col <= row) ? __expf(acc[mi][ni][r]) : 0.0f;
          C[(size_t)row * N + col] = f2bf(ev);
          partial += ev;
        }
#pragma unroll
        for (int o = 1; o < 16; o <<= 1) partial += __shfl_xor(partial, o, 64);
        if (l15 == 0) atomicAdd(&ls[row], partial);
      }
    return;
  } else {
    const float scale = (z == 0) ? scale0 : scale1;
    const bool storeBf = (OUTK == 1) || (OUTK == 2 && *flag != 0);
#pragma unroll
    for (int mi = 0; mi < MI; mi++)
#pragma unroll
      for (int ni = 0; ni < 4; ni++)
#pragma unroll
        for (int r = 0; r < 4; r++) {
          const int lrow = wm + mi * 16 + quad * 4 + r;
          const int row = m0 + lrow;
          const int col = n0 + wn + ni * 16 + l15;
          const float sc = (EPI == 2) ? lsh[lrow] : scale;
          const float vv = acc[mi][ni][r] * sc;
          if (storeBf) {
            ushort* C = (ushort*)Cv + zc;
            C[(size_t)row * N + col] = f2bf(vv);
          } else {
            float* C = (float*)Cv + zc;
            C[(size_t)row * N + col] = vv;
          }
        }
  }
}

// Workspace (MB): 0 flag | 1 wt(6) | 7 xb(16) | 23 q(16) | 39 k(16) |
// 55 Vt_all [1024 x 8192] (16) | 71 E bf16(32) | 103 lsum(32KB)
extern "C" void kernel_launch(void* const* d_in, const int* in_sizes, int n_in,
                              void* d_out, int out_size, void* d_ws,
                              size_t ws_size, hipStream_t stream) {
  char* ws = (char*)d_ws;
  const size_t MB = 1024 * 1024;
  int* flag = (int*)ws;
  ushort* wt = (ushort*)(ws + 1 * MB);
  ushort* xb = (ushort*)(ws + 7 * MB);
  ushort* q = (ushort*)(ws + 23 * MB);
  ushort* vt = (ushort*)(ws + 55 * MB);
  ushort* sc = (ushort*)(ws + 71 * MB);
  float* lsum = (float*)(ws + 103 * MB);

  prep<<<dim3(1288), 256, 0, stream>>>(d_in[0], d_in[1], d_in[2], d_in[3], xb,
                                       wt, flag, lsum);

  // Q,K projections: exactly 256 blocks = 1 clean round (1 block/CU).
  gemm8<0><<<dim3(256), 512, 0, stream>>>(xb, wt, nullptr, (void*)q, nullptr,
                                          nullptr);

  // Merged: blocks [0,144) -> E = exp(Q K^T) causal (exact tri list) + lsum;
  //         blocks [144,272) -> Vt = Wv^T X^T [1024x8192].
  gemm8<1><<<dim3(272), 512, 0, stream>>>(q, wt, xb, (void*)sc, (void*)vt,
                                          lsum);

  // out = diag(1/l) * (E @ V^T); BN=64 + SWIZ 5: 1024 blocks, 4/CU,
  // balanced 34 K-steps per CU with true 4-deep overlap.
  gemm_t<2, 2, 1, 5, 2048, 1024, 2048, (long)SEQ * SEQ, 2048L,
         (long)SEQ * DIM, 8192L, 64>
      <<<dim3(16, 16, 4), 256, 0, stream>>>(sc, vt, d_out, flag, lsum, 1.0f,
                                            1.0f);
}